// Round 2
// baseline (789.594 us; speedup 1.0000x reference)
//
#include <hip/hip_runtime.h>
#include <hip/hip_bf16.h>

typedef __bf16 bf16;
typedef __bf16 bf16x8 __attribute__((ext_vector_type(8)));
typedef __bf16 bf16x4 __attribute__((ext_vector_type(4)));
typedef float f32x4 __attribute__((ext_vector_type(4)));

#define NT 8192   // tokens = B*S
#define DD 1024   // model dim
#define HH 4096   // hidden dim
#define NE 8      // experts

__device__ __forceinline__ void gload_lds16(const void* g, void* l) {
  __builtin_amdgcn_global_load_lds(
      (__attribute__((address_space(1))) void*)(g),
      (__attribute__((address_space(3))) void*)(l), 16, 0, 0);
}

// ---------------- x -> bf16 ----------------
__global__ void k_convert_x(const float* __restrict__ x, bf16* __restrict__ xb) {
  int i = blockIdx.x * blockDim.x + threadIdx.x;  // 4 elems per thread
  float4 v = reinterpret_cast<const float4*>(x)[i];
  bf16x4 o;
  o[0] = (bf16)v.x; o[1] = (bf16)v.y; o[2] = (bf16)v.z; o[3] = (bf16)v.w;
  reinterpret_cast<bf16x4*>(xb)[i] = o;
}

// ------------- [E][R][C] f32 -> [E][C][R] bf16 -------------
__global__ void k_transpose(const float* __restrict__ in, bf16* __restrict__ out,
                            int R, int C) {
  __shared__ float tile[32][33];
  int e = blockIdx.z;
  int c0 = blockIdx.x * 32, r0 = blockIdx.y * 32;
  int tx = threadIdx.x, ty = threadIdx.y;  // 32 x 8
  const float* ip = in + (size_t)e * R * C;
  bf16* op = out + (size_t)e * R * C;
#pragma unroll
  for (int i = 0; i < 4; ++i)
    tile[ty + i * 8][tx] = ip[(size_t)(r0 + ty + i * 8) * C + c0 + tx];
  __syncthreads();
#pragma unroll
  for (int i = 0; i < 4; ++i)
    op[(size_t)(c0 + ty + i * 8) * R + r0 + tx] = (bf16)tile[tx][ty + i * 8];
}

// ---------------- router ----------------
__global__ __launch_bounds__(256) void k_router(
    const float* __restrict__ x, const float* __restrict__ Wr,
    float* __restrict__ gate, int* __restrict__ lists, int* __restrict__ counts,
    float* __restrict__ auxpart) {
  __shared__ float bp[4][8];
  int wv = threadIdx.x >> 6, l = threadIdx.x & 63;
  int t = blockIdx.x * 4 + wv;
  const float* xr = x + (size_t)t * DD;
  float p[8];
#pragma unroll
  for (int e = 0; e < 8; ++e) p[e] = 0.f;
#pragma unroll
  for (int c = 0; c < 4; ++c) {
    int d0 = c * 256 + l * 4;
    float4 xv = *reinterpret_cast<const float4*>(xr + d0);
    float xs[4] = {xv.x, xv.y, xv.z, xv.w};
#pragma unroll
    for (int j = 0; j < 4; ++j) {
      float4 w0 = *reinterpret_cast<const float4*>(Wr + (size_t)(d0 + j) * 8);
      float4 w1 = *reinterpret_cast<const float4*>(Wr + (size_t)(d0 + j) * 8 + 4);
      p[0] += xs[j] * w0.x; p[1] += xs[j] * w0.y;
      p[2] += xs[j] * w0.z; p[3] += xs[j] * w0.w;
      p[4] += xs[j] * w1.x; p[5] += xs[j] * w1.y;
      p[6] += xs[j] * w1.z; p[7] += xs[j] * w1.w;
    }
  }
#pragma unroll
  for (int off = 32; off >= 1; off >>= 1)
#pragma unroll
    for (int e = 0; e < 8; ++e) p[e] += __shfl_down(p[e], off);
  if (l == 0) {
    float m = p[0];
#pragma unroll
    for (int e = 1; e < 8; ++e) m = fmaxf(m, p[e]);
    float pr[8], s = 0.f;
#pragma unroll
    for (int e = 0; e < 8; ++e) { pr[e] = expf(p[e] - m); s += pr[e]; }
    float inv = 1.f / s;
#pragma unroll
    for (int e = 0; e < 8; ++e) pr[e] *= inv;
    int i1 = 0;
#pragma unroll
    for (int e = 1; e < 8; ++e) if (pr[e] > pr[i1]) i1 = e;
    int i2 = (i1 == 0) ? 1 : 0;
#pragma unroll
    for (int e = 0; e < 8; ++e) if (e != i1 && pr[e] > pr[i2]) i2 = e;
    float wsum = pr[i1] + pr[i2];
    gate[t * 8 + i1] = pr[i1] / wsum;
    gate[t * 8 + i2] = pr[i2] / wsum;
    int p1 = atomicAdd(&counts[i1], 1); lists[i1 * NT + p1] = t;
    int p2 = atomicAdd(&counts[i2], 1); lists[i2 * NT + p2] = t;
#pragma unroll
    for (int e = 0; e < 8; ++e) bp[wv][e] = pr[e];
  }
  __syncthreads();
  if (threadIdx.x < 8) {
    float s = bp[0][threadIdx.x] + bp[1][threadIdx.x] +
              bp[2][threadIdx.x] + bp[3][threadIdx.x];
    auxpart[blockIdx.x * 8 + threadIdx.x] = s;
  }
}

// ------------- aux loss + prefix offsets -------------
__global__ void k_finalize(const int* __restrict__ counts, int* __restrict__ offs,
                           const float* __restrict__ auxpart, float* __restrict__ aux_out) {
  __shared__ float sh[32][8];
  int e = threadIdx.x & 7, chunk = threadIdx.x >> 3;  // 256 threads
  float s = 0.f;
  for (int b = chunk * 64; b < chunk * 64 + 64; ++b) s += auxpart[b * 8 + e];
  sh[chunk][e] = s;
  __syncthreads();
  if (threadIdx.x < 8) {
    float tot = 0.f;
    for (int c = 0; c < 32; ++c) tot += sh[c][threadIdx.x];
    float d = tot * (1.f / 8192.f) - 0.125f;
    sh[0][threadIdx.x] = d * d;
  }
  __syncthreads();
  if (threadIdx.x == 0) {
    float loss = 0.f;
    for (int e2 = 0; e2 < 8; ++e2) loss += sh[0][e2];
    aux_out[0] = loss;
    int o = 0;
    for (int e2 = 0; e2 < 8; ++e2) { offs[e2] = o; o += counts[e2]; }
    offs[8] = o;
  }
}

// ======== grouped expert GEMM, 256x256 tile, BK=64, 8-phase counted-vmcnt ========
// C[M x NTOT] = A[M x KTOT] @ B^T  (B stored [NTOT][KTOT] bf16)
// 8 waves (2M x 4N), per-wave output 128x64. LDS 128KB: 2 dbuf x (A 32K + B 32K),
// each tile split in 2 halves of [128 rows][64 k] staged by 2 global_load_lds/thread.
// Swizzle: 16B chunk c of row r holds logical chunk c^(r&7) (both-sides involution).

#define BARX() do { __builtin_amdgcn_sched_barrier(0); asm volatile("" ::: "memory"); \
                    __builtin_amdgcn_s_barrier(); asm volatile("" ::: "memory"); \
                    __builtin_amdgcn_sched_barrier(0); } while (0)
#define VM2() asm volatile("s_waitcnt vmcnt(2)" ::: "memory")
#define VM0() asm volatile("s_waitcnt vmcnt(0)" ::: "memory")
#define P1() __builtin_amdgcn_s_setprio(1)
#define P0() __builtin_amdgcn_s_setprio(0)

#define STAGE_A(b, h, kt) do { \
  gload_lds16(aP[h][0] + (size_t)(kt) * 64, &lds[(b)*65536 + (h)*16384 + w*1024]); \
  gload_lds16(aP[h][1] + (size_t)(kt) * 64, &lds[(b)*65536 + (h)*16384 + 8192 + w*1024]); } while (0)
#define STAGE_B(b, h, kt) do { \
  gload_lds16(bP[h][0] + (size_t)(kt) * 64, &lds[(b)*65536 + 32768 + (h)*16384 + w*1024]); \
  gload_lds16(bP[h][1] + (size_t)(kt) * 64, &lds[(b)*65536 + 32768 + (h)*16384 + 8192 + w*1024]); } while (0)

#define LDA(b, qm) do { \
  _Pragma("unroll") for (int mi = 0; mi < 4; ++mi) \
  _Pragma("unroll") for (int kk = 0; kk < 2; ++kk) \
    af[mi][kk] = *reinterpret_cast<const bf16x8*>(&lds[(b)*65536 + wm*16384 + \
        ((qm)*64 + mi*16 + lr)*128 + (((kk*4 + lk) ^ (lr & 7)) << 4)]); } while (0)

#define LDB(b, qn, st) do { \
  _Pragma("unroll") for (int ni = 0; ni < 2; ++ni) \
  _Pragma("unroll") for (int kk = 0; kk < 2; ++kk) \
    bfr[st][ni][kk] = *reinterpret_cast<const bf16x8*>(&lds[(b)*65536 + 32768 + bh*16384 + \
        (brow + (qn)*32 + ni*16)*128 + (((kk*4 + lk) ^ (lr & 7)) << 4)]); } while (0)

#define MMA(qm, qn, st) do { \
  _Pragma("unroll") for (int kk = 0; kk < 2; ++kk) \
  _Pragma("unroll") for (int mi = 0; mi < 4; ++mi) \
  _Pragma("unroll") for (int ni = 0; ni < 2; ++ni) \
    acc[(qm)*4 + mi][(qn)*2 + ni] = __builtin_amdgcn_mfma_f32_16x16x32_bf16( \
        af[mi][kk], bfr[st][ni][kk], acc[(qm)*4 + mi][(qn)*2 + ni], 0, 0, 0); } while (0)

template <int KTOT, int NTOT, bool IS_G1>
__global__ __launch_bounds__(512, 2) void k_moe_gemm(
    const bf16* __restrict__ A, const bf16* __restrict__ Bw,
    bf16* __restrict__ Hout, float* __restrict__ Yout,
    const int* __restrict__ lists, const int* __restrict__ counts,
    const int* __restrict__ offs, const float* __restrict__ gate) {
  const int e = blockIdx.z;
  const int count = counts[e];
  const int m0 = blockIdx.y * 256;
  if (m0 >= count) return;
  const int n0 = blockIdx.x * 256;
  const int tid = threadIdx.x;
  const int w = tid >> 6, l = tid & 63;
  const int wm = w >> 2, wn = w & 3;
  const int lr = l & 15, lk = l >> 4;
  const int bh = wn >> 1;
  const int brow = (wn & 1) * 64 + lr;

  __shared__ __align__(16) char lds[131072];

  const int hoff = offs[e];

  // staging source pointers: thread covers row j*64 + w*8 + (l>>3), chunk (l&7),
  // source column pre-swizzled with the same involution the reads use.
  const int srow = w * 8 + (l >> 3);
  const int schunk = ((l & 7) ^ (srow & 7)) * 8;  // elems
  const bf16* aP[2][2];
  const bf16* bP[2][2];
#pragma unroll
  for (int h = 0; h < 2; ++h)
#pragma unroll
    for (int j = 0; j < 2; ++j) {
      int rl = h * 128 + j * 64 + srow;
      int mrow = m0 + rl; if (mrow > count - 1) mrow = count - 1;
      size_t arow = IS_G1 ? (size_t)lists[e * NT + mrow] : (size_t)(hoff + mrow);
      aP[h][j] = A + arow * KTOT + schunk;
      bP[h][j] = Bw + (size_t)e * NTOT * KTOT + (size_t)(n0 + rl) * KTOT + schunk;
    }

  f32x4 acc[8][4];
#pragma unroll
  for (int mf = 0; mf < 8; ++mf)
#pragma unroll
    for (int nf = 0; nf < 4; ++nf) acc[mf][nf] = (f32x4){0.f, 0.f, 0.f, 0.f};

  bf16x8 af[4][2];
  bf16x8 bfr[2][2][2];

  // prologue: tile0 fully, tile1 A-h0; gate leaves tile1-A-h0 in flight
  STAGE_A(0, 0, 0); STAGE_A(0, 1, 0); STAGE_B(0, 0, 0); STAGE_B(0, 1, 0);
  STAGE_A(1, 0, 1);
  VM2();
  BARX();

  const int NIT = KTOT / 128;
#pragma unroll 1
  for (int ii = 0; ii < NIT; ++ii) {
    const int t = 2 * ii;
    const bool full = (ii != NIT - 1);
    // ph0: read buf0 A[qm0], B[qn0]; stage (t+1) A-h1 -> buf1
    LDA(0, 0); LDB(0, 0, 0);
    STAGE_A(1, 1, t + 1);
    BARX(); P1(); MMA(0, 0, 0); P0(); BARX();
    // ph1: read B[qn1]; stage (t+1) B-h0
    LDB(0, 1, 1);
    STAGE_B(1, 0, t + 1);
    BARX(); P1(); MMA(0, 1, 1); P0(); BARX();
    // ph2: read A[qm1]; stage (t+1) B-h1
    LDA(0, 1);
    STAGE_B(1, 1, t + 1);
    BARX(); P1(); MMA(1, 1, 1); P0(); BARX();
    // ph3: stage (t+2) A-h0 -> buf0; gate: tile t+1 fully landed
    if (full) STAGE_A(0, 0, t + 2);
    BARX(); P1(); MMA(1, 0, 0); P0();
    if (full) { VM2(); } else { VM0(); }
    BARX();
    // ph4: read buf1 A[qm0], B[qn0]; stage (t+2) A-h1
    LDA(1, 0); LDB(1, 0, 0);
    if (full) STAGE_A(0, 1, t + 2);
    BARX(); P1(); MMA(0, 0, 0); P0(); BARX();
    // ph5: read B[qn1]; stage (t+2) B-h0
    LDB(1, 1, 1);
    if (full) STAGE_B(0, 0, t + 2);
    BARX(); P1(); MMA(0, 1, 1); P0(); BARX();
    // ph6: read A[qm1]; stage (t+2) B-h1
    LDA(1, 1);
    if (full) STAGE_B(0, 1, t + 2);
    BARX(); P1(); MMA(1, 1, 1); P0(); BARX();
    // ph7: stage (t+3) A-h0 -> buf1; gate: tile t+2 fully landed
    if (full) STAGE_A(1, 0, t + 3);
    BARX(); P1(); MMA(1, 0, 0); P0();
    if (full) { VM2(); } else { VM0(); }
    BARX();
  }

  // epilogue: acc[mf][nf] -> rows (mf>>2)*64+(mf&3)*16+lk*4+jj, cols (nf>>1)*32+(nf&1)*16+lr
#pragma unroll
  for (int mf = 0; mf < 8; ++mf) {
    const int rowoff = (mf >> 2) * 64 + (mf & 3) * 16;
#pragma unroll
    for (int jj = 0; jj < 4; ++jj) {
      int m = m0 + wm * 128 + rowoff + lk * 4 + jj;
      if (m < count) {
        if (IS_G1) {
          size_t base = (size_t)(hoff + m) * NTOT + n0 + wn * 64 + lr;
#pragma unroll
          for (int nf = 0; nf < 4; ++nf) {
            float v = acc[mf][nf][jj];
            float g = 0.5f * v * (1.0f + erff(v * 0.70710678118654752f));
            Hout[base + (nf >> 1) * 32 + (nf & 1) * 16] = (bf16)g;
          }
        } else {
          int tok = lists[e * NT + m];
          float wg = gate[tok * 8 + e];
          size_t base = (size_t)tok * 1024 + n0 + wn * 64 + lr;
#pragma unroll
          for (int nf = 0; nf < 4; ++nf)
            unsafeAtomicAdd(&Yout[base + (nf >> 1) * 32 + (nf & 1) * 16],
                            wg * acc[mf][nf][jj]);
        }
      }
    }
  }
}

#undef BARX
#undef VM2
#undef VM0
#undef P1
#undef P0
#undef STAGE_A
#undef STAGE_B
#undef LDA
#undef LDB
#undef MMA

extern "C" void kernel_launch(void* const* d_in, const int* in_sizes, int n_in,
                              void* d_out, int out_size, void* d_ws, size_t ws_size,
                              hipStream_t stream) {
  const float* x = (const float*)d_in[0];
  const float* Wr = (const float*)d_in[1];
  const float* W1 = (const float*)d_in[2];
  const float* W2 = (const float*)d_in[3];
  float* out = (float*)d_out;

  char* ws = (char*)d_ws;
  size_t off = 0;
  bf16* Xb = (bf16*)(ws + off);  off += (size_t)NT * DD * 2;        // 16.8 MB
  bf16* W1T = (bf16*)(ws + off); off += (size_t)NE * DD * HH * 2;   // 67 MB
  bf16* W2T = (bf16*)(ws + off); off += (size_t)NE * DD * HH * 2;   // 67 MB
  bf16* Hb = (bf16*)(ws + off);  off += (size_t)NT * 2 * HH * 2;    // 134 MB (16384 rows)
  float* gate = (float*)(ws + off); off += (size_t)NT * 8 * 4;
  int* lists = (int*)(ws + off);    off += (size_t)NE * NT * 4;
  int* counts = (int*)(ws + off);   off += 64;
  int* offs = (int*)(ws + off);     off += 64;
  float* auxpart = (float*)(ws + off); off += (size_t)(NT / 4) * 8 * 4;

  hipMemsetAsync(d_out, 0, (size_t)out_size * 4, stream);
  hipMemsetAsync(counts, 0, 64, stream);

  k_convert_x<<<NT * DD / 4 / 256, 256, 0, stream>>>(x, Xb);
  k_transpose<<<dim3(HH / 32, DD / 32, NE), dim3(32, 8), 0, stream>>>(W1, W1T, DD, HH);
  k_transpose<<<dim3(DD / 32, HH / 32, NE), dim3(32, 8), 0, stream>>>(W2, W2T, HH, DD);
  k_router<<<NT / 4, 256, 0, stream>>>(x, Wr, gate, lists, counts, auxpart);
  k_finalize<<<1, 256, 0, stream>>>(counts, offs, auxpart, out + (size_t)NT * DD);
  k_moe_gemm<DD, HH, true><<<dim3(HH / 256, 32, NE), 512, 0, stream>>>(
      Xb, W1T, Hb, nullptr, lists, counts, offs, gate);
  k_moe_gemm<HH, DD, false><<<dim3(DD / 256, 32, NE), 512, 0, stream>>>(
      Hb, W2T, nullptr, out, lists, counts, offs, gate);
}

// Round 3
// 787.141 us; speedup vs baseline: 1.0031x; 1.0031x over previous
//
#include <hip/hip_runtime.h>
#include <hip/hip_bf16.h>

typedef __bf16 bf16;
typedef __bf16 bf16x8 __attribute__((ext_vector_type(8)));
typedef __bf16 bf16x4 __attribute__((ext_vector_type(4)));
typedef float f32x4 __attribute__((ext_vector_type(4)));

#define NT 8192   // tokens = B*S
#define DD 1024   // model dim
#define HH 4096   // hidden dim
#define NE 8      // experts

__device__ __forceinline__ void gload_lds16(const void* g, void* l) {
  __builtin_amdgcn_global_load_lds(
      (__attribute__((address_space(1))) void*)(g),
      (__attribute__((address_space(3))) void*)(l), 16, 0, 0);
}

// ---------------- x -> bf16 ----------------
__global__ void k_convert_x(const float* __restrict__ x, bf16* __restrict__ xb) {
  int i = blockIdx.x * blockDim.x + threadIdx.x;  // 4 elems per thread
  float4 v = reinterpret_cast<const float4*>(x)[i];
  bf16x4 o;
  o[0] = (bf16)v.x; o[1] = (bf16)v.y; o[2] = (bf16)v.z; o[3] = (bf16)v.w;
  reinterpret_cast<bf16x4*>(xb)[i] = o;
}

// ------------- [E][R][C] f32 -> [E][C][R] bf16 -------------
__global__ void k_transpose(const float* __restrict__ in, bf16* __restrict__ out,
                            int R, int C) {
  __shared__ float tile[32][33];
  int e = blockIdx.z;
  int c0 = blockIdx.x * 32, r0 = blockIdx.y * 32;
  int tx = threadIdx.x, ty = threadIdx.y;  // 32 x 8
  const float* ip = in + (size_t)e * R * C;
  bf16* op = out + (size_t)e * R * C;
#pragma unroll
  for (int i = 0; i < 4; ++i)
    tile[ty + i * 8][tx] = ip[(size_t)(r0 + ty + i * 8) * C + c0 + tx];
  __syncthreads();
#pragma unroll
  for (int i = 0; i < 4; ++i)
    op[(size_t)(c0 + ty + i * 8) * R + r0 + tx] = (bf16)tile[tx][ty + i * 8];
}

// ---------------- router ----------------
__global__ __launch_bounds__(256) void k_router(
    const float* __restrict__ x, const float* __restrict__ Wr,
    float* __restrict__ gate, int* __restrict__ lists, int* __restrict__ counts,
    float* __restrict__ auxpart) {
  __shared__ float bp[4][8];
  int wv = threadIdx.x >> 6, l = threadIdx.x & 63;
  int t = blockIdx.x * 4 + wv;
  const float* xr = x + (size_t)t * DD;
  float p[8];
#pragma unroll
  for (int e = 0; e < 8; ++e) p[e] = 0.f;
#pragma unroll
  for (int c = 0; c < 4; ++c) {
    int d0 = c * 256 + l * 4;
    float4 xv = *reinterpret_cast<const float4*>(xr + d0);
    float xs[4] = {xv.x, xv.y, xv.z, xv.w};
#pragma unroll
    for (int j = 0; j < 4; ++j) {
      float4 w0 = *reinterpret_cast<const float4*>(Wr + (size_t)(d0 + j) * 8);
      float4 w1 = *reinterpret_cast<const float4*>(Wr + (size_t)(d0 + j) * 8 + 4);
      p[0] += xs[j] * w0.x; p[1] += xs[j] * w0.y;
      p[2] += xs[j] * w0.z; p[3] += xs[j] * w0.w;
      p[4] += xs[j] * w1.x; p[5] += xs[j] * w1.y;
      p[6] += xs[j] * w1.z; p[7] += xs[j] * w1.w;
    }
  }
#pragma unroll
  for (int off = 32; off >= 1; off >>= 1)
#pragma unroll
    for (int e = 0; e < 8; ++e) p[e] += __shfl_down(p[e], off);
  if (l == 0) {
    float m = p[0];
#pragma unroll
    for (int e = 1; e < 8; ++e) m = fmaxf(m, p[e]);
    float pr[8], s = 0.f;
#pragma unroll
    for (int e = 0; e < 8; ++e) { pr[e] = expf(p[e] - m); s += pr[e]; }
    float inv = 1.f / s;
#pragma unroll
    for (int e = 0; e < 8; ++e) pr[e] *= inv;
    int i1 = 0;
#pragma unroll
    for (int e = 1; e < 8; ++e) if (pr[e] > pr[i1]) i1 = e;
    int i2 = (i1 == 0) ? 1 : 0;
#pragma unroll
    for (int e = 0; e < 8; ++e) if (e != i1 && pr[e] > pr[i2]) i2 = e;
    float wsum = pr[i1] + pr[i2];
    gate[t * 8 + i1] = pr[i1] / wsum;
    gate[t * 8 + i2] = pr[i2] / wsum;
    int p1 = atomicAdd(&counts[i1], 1); lists[i1 * NT + p1] = t;
    int p2 = atomicAdd(&counts[i2], 1); lists[i2 * NT + p2] = t;
#pragma unroll
    for (int e = 0; e < 8; ++e) bp[wv][e] = pr[e];
  }
  __syncthreads();
  if (threadIdx.x < 8) {
    float s = bp[0][threadIdx.x] + bp[1][threadIdx.x] +
              bp[2][threadIdx.x] + bp[3][threadIdx.x];
    auxpart[blockIdx.x * 8 + threadIdx.x] = s;
  }
}

// ------------- aux loss + prefix offsets -------------
__global__ void k_finalize(const int* __restrict__ counts, int* __restrict__ offs,
                           const float* __restrict__ auxpart, float* __restrict__ aux_out) {
  __shared__ float sh[32][8];
  int e = threadIdx.x & 7, chunk = threadIdx.x >> 3;  // 256 threads
  float s = 0.f;
  for (int b = chunk * 64; b < chunk * 64 + 64; ++b) s += auxpart[b * 8 + e];
  sh[chunk][e] = s;
  __syncthreads();
  if (threadIdx.x < 8) {
    float tot = 0.f;
    for (int c = 0; c < 32; ++c) tot += sh[c][threadIdx.x];
    float d = tot * (1.f / 8192.f) - 0.125f;
    sh[0][threadIdx.x] = d * d;
  }
  __syncthreads();
  if (threadIdx.x == 0) {
    float loss = 0.f;
    for (int e2 = 0; e2 < 8; ++e2) loss += sh[0][e2];
    aux_out[0] = loss;
    int o = 0;
    for (int e2 = 0; e2 < 8; ++e2) { offs[e2] = o; o += counts[e2]; }
    offs[8] = o;
  }
}

// ======== grouped expert GEMM, 256x256 tile, BK=64, 8-phase counted-vmcnt ========
// C[M x NTOT] = A[M x KTOT] @ B^T  (B stored [NTOT][KTOT] bf16)
// 8 waves (2M x 4N), per-wave output 128x64. LDS 128KB: 2 dbuf x (A 32K + B 32K),
// each tile split in 2 halves of [128 rows][64 k] staged by 2 global_load_lds/thread.
// Swizzle: 16B chunk c of row r holds logical chunk c^(r&7) (both-sides involution).
// R3 change: plain s_barrier + compiler memory fence ONLY (no sched_barrier(0) —
// m141 pathology). Fences order memory ops; MFMA/VALU schedule freely.

#define BARX() do { asm volatile("" ::: "memory"); \
                    __builtin_amdgcn_s_barrier(); \
                    asm volatile("" ::: "memory"); } while (0)
#define VM2() asm volatile("s_waitcnt vmcnt(2)" ::: "memory")
#define VM0() asm volatile("s_waitcnt vmcnt(0)" ::: "memory")
#define P1() __builtin_amdgcn_s_setprio(1)
#define P0() __builtin_amdgcn_s_setprio(0)

#define STAGE_A(b, h, kt) do { \
  gload_lds16(aP[h][0] + (size_t)(kt) * 64, &lds[(b)*65536 + (h)*16384 + w*1024]); \
  gload_lds16(aP[h][1] + (size_t)(kt) * 64, &lds[(b)*65536 + (h)*16384 + 8192 + w*1024]); } while (0)
#define STAGE_B(b, h, kt) do { \
  gload_lds16(bP[h][0] + (size_t)(kt) * 64, &lds[(b)*65536 + 32768 + (h)*16384 + w*1024]); \
  gload_lds16(bP[h][1] + (size_t)(kt) * 64, &lds[(b)*65536 + 32768 + (h)*16384 + 8192 + w*1024]); } while (0)

#define LDA(b, qm) do { \
  _Pragma("unroll") for (int mi = 0; mi < 4; ++mi) \
  _Pragma("unroll") for (int kk = 0; kk < 2; ++kk) \
    af[mi][kk] = *reinterpret_cast<const bf16x8*>(&lds[(b)*65536 + wm*16384 + \
        ((qm)*64 + mi*16 + lr)*128 + (((kk*4 + lk) ^ (lr & 7)) << 4)]); } while (0)

#define LDB(b, qn, st) do { \
  _Pragma("unroll") for (int ni = 0; ni < 2; ++ni) \
  _Pragma("unroll") for (int kk = 0; kk < 2; ++kk) \
    bfr[st][ni][kk] = *reinterpret_cast<const bf16x8*>(&lds[(b)*65536 + 32768 + bh*16384 + \
        (brow + (qn)*32 + ni*16)*128 + (((kk*4 + lk) ^ (lr & 7)) << 4)]); } while (0)

#define MMA(qm, qn, st) do { \
  _Pragma("unroll") for (int kk = 0; kk < 2; ++kk) \
  _Pragma("unroll") for (int mi = 0; mi < 4; ++mi) \
  _Pragma("unroll") for (int ni = 0; ni < 2; ++ni) \
    acc[(qm)*4 + mi][(qn)*2 + ni] = __builtin_amdgcn_mfma_f32_16x16x32_bf16( \
        af[mi][kk], bfr[st][ni][kk], acc[(qm)*4 + mi][(qn)*2 + ni], 0, 0, 0); } while (0)

template <int KTOT, int NTOT, bool IS_G1>
__global__ __launch_bounds__(512, 2) void k_moe_gemm(
    const bf16* __restrict__ A, const bf16* __restrict__ Bw,
    bf16* __restrict__ Hout, float* __restrict__ Yout,
    const int* __restrict__ lists, const int* __restrict__ counts,
    const int* __restrict__ offs, const float* __restrict__ gate) {
  const int e = blockIdx.z;
  const int count = counts[e];
  const int m0 = blockIdx.y * 256;
  if (m0 >= count) return;
  const int n0 = blockIdx.x * 256;
  const int tid = threadIdx.x;
  const int w = tid >> 6, l = tid & 63;
  const int wm = w >> 2, wn = w & 3;
  const int lr = l & 15, lk = l >> 4;
  const int bh = wn >> 1;
  const int brow = (wn & 1) * 64 + lr;

  __shared__ __align__(16) char lds[131072];

  const int hoff = offs[e];

  // staging source pointers: thread covers row j*64 + w*8 + (l>>3), chunk (l&7),
  // source column pre-swizzled with the same involution the reads use.
  const int srow = w * 8 + (l >> 3);
  const int schunk = ((l & 7) ^ (srow & 7)) * 8;  // elems
  const bf16* aP[2][2];
  const bf16* bP[2][2];
#pragma unroll
  for (int h = 0; h < 2; ++h)
#pragma unroll
    for (int j = 0; j < 2; ++j) {
      int rl = h * 128 + j * 64 + srow;
      int mrow = m0 + rl; if (mrow > count - 1) mrow = count - 1;
      size_t arow = IS_G1 ? (size_t)lists[e * NT + mrow] : (size_t)(hoff + mrow);
      aP[h][j] = A + arow * KTOT + schunk;
      bP[h][j] = Bw + (size_t)e * NTOT * KTOT + (size_t)(n0 + rl) * KTOT + schunk;
    }

  f32x4 acc[8][4];
#pragma unroll
  for (int mf = 0; mf < 8; ++mf)
#pragma unroll
    for (int nf = 0; nf < 4; ++nf) acc[mf][nf] = (f32x4){0.f, 0.f, 0.f, 0.f};

  bf16x8 af[4][2];
  bf16x8 bfr[2][2][2];

  // prologue: tile0 fully, tile1 A-h0; gate leaves tile1-A-h0 in flight
  STAGE_A(0, 0, 0); STAGE_A(0, 1, 0); STAGE_B(0, 0, 0); STAGE_B(0, 1, 0);
  STAGE_A(1, 0, 1);
  VM2();
  BARX();

  const int NIT = KTOT / 128;
#pragma unroll 1
  for (int ii = 0; ii < NIT; ++ii) {
    const int t = 2 * ii;
    const bool full = (ii != NIT - 1);
    // ph0: read buf0 A[qm0], B[qn0]; stage (t+1) A-h1 -> buf1
    LDA(0, 0); LDB(0, 0, 0);
    STAGE_A(1, 1, t + 1);
    BARX(); P1(); MMA(0, 0, 0); P0(); BARX();
    // ph1: read B[qn1]; stage (t+1) B-h0
    LDB(0, 1, 1);
    STAGE_B(1, 0, t + 1);
    BARX(); P1(); MMA(0, 1, 1); P0(); BARX();
    // ph2: read A[qm1]; stage (t+1) B-h1
    LDA(0, 1);
    STAGE_B(1, 1, t + 1);
    BARX(); P1(); MMA(1, 1, 1); P0(); BARX();
    // ph3: stage (t+2) A-h0 -> buf0; gate: tile t+1 fully landed
    if (full) STAGE_A(0, 0, t + 2);
    BARX(); P1(); MMA(1, 0, 0); P0();
    if (full) { VM2(); } else { VM0(); }
    BARX();
    // ph4: read buf1 A[qm0], B[qn0]; stage (t+2) A-h1
    LDA(1, 0); LDB(1, 0, 0);
    if (full) STAGE_A(0, 1, t + 2);
    BARX(); P1(); MMA(0, 0, 0); P0(); BARX();
    // ph5: read B[qn1]; stage (t+2) B-h0
    LDB(1, 1, 1);
    if (full) STAGE_B(0, 0, t + 2);
    BARX(); P1(); MMA(0, 1, 1); P0(); BARX();
    // ph6: read A[qm1]; stage (t+2) B-h1
    LDA(1, 1);
    if (full) STAGE_B(0, 1, t + 2);
    BARX(); P1(); MMA(1, 1, 1); P0(); BARX();
    // ph7: stage (t+3) A-h0 -> buf1; gate: tile t+2 fully landed
    if (full) STAGE_A(1, 0, t + 3);
    BARX(); P1(); MMA(1, 0, 0); P0();
    if (full) { VM2(); } else { VM0(); }
    BARX();
  }

  // epilogue: acc[mf][nf] -> rows (mf>>2)*64+(mf&3)*16+lk*4+jj, cols (nf>>1)*32+(nf&1)*16+lr
#pragma unroll
  for (int mf = 0; mf < 8; ++mf) {
    const int rowoff = (mf >> 2) * 64 + (mf & 3) * 16;
#pragma unroll
    for (int jj = 0; jj < 4; ++jj) {
      int m = m0 + wm * 128 + rowoff + lk * 4 + jj;
      if (m < count) {
        if (IS_G1) {
          size_t base = (size_t)(hoff + m) * NTOT + n0 + wn * 64 + lr;
#pragma unroll
          for (int nf = 0; nf < 4; ++nf) {
            float v = acc[mf][nf][jj];
            float g = 0.5f * v * (1.0f + erff(v * 0.70710678118654752f));
            Hout[base + (nf >> 1) * 32 + (nf & 1) * 16] = (bf16)g;
          }
        } else {
          int tok = lists[e * NT + m];
          float wg = gate[tok * 8 + e];
          size_t base = (size_t)tok * 1024 + n0 + wn * 64 + lr;
#pragma unroll
          for (int nf = 0; nf < 4; ++nf)
            unsafeAtomicAdd(&Yout[base + (nf >> 1) * 32 + (nf & 1) * 16],
                            wg * acc[mf][nf][jj]);
        }
      }
    }
  }
}

#undef BARX
#undef VM2
#undef VM0
#undef P1
#undef P0
#undef STAGE_A
#undef STAGE_B
#undef LDA
#undef LDB
#undef MMA

extern "C" void kernel_launch(void* const* d_in, const int* in_sizes, int n_in,
                              void* d_out, int out_size, void* d_ws, size_t ws_size,
                              hipStream_t stream) {
  const float* x = (const float*)d_in[0];
  const float* Wr = (const float*)d_in[1];
  const float* W1 = (const float*)d_in[2];
  const float* W2 = (const float*)d_in[3];
  float* out = (float*)d_out;

  char* ws = (char*)d_ws;
  size_t off = 0;
  bf16* Xb = (bf16*)(ws + off);  off += (size_t)NT * DD * 2;        // 16.8 MB
  bf16* W1T = (bf16*)(ws + off); off += (size_t)NE * DD * HH * 2;   // 67 MB
  bf16* W2T = (bf16*)(ws + off); off += (size_t)NE * DD * HH * 2;   // 67 MB
  bf16* Hb = (bf16*)(ws + off);  off += (size_t)NT * 2 * HH * 2;    // 134 MB (16384 rows)
  float* gate = (float*)(ws + off); off += (size_t)NT * 8 * 4;
  int* lists = (int*)(ws + off);    off += (size_t)NE * NT * 4;
  int* counts = (int*)(ws + off);   off += 64;
  int* offs = (int*)(ws + off);     off += 64;
  float* auxpart = (float*)(ws + off); off += (size_t)(NT / 4) * 8 * 4;

  hipMemsetAsync(d_out, 0, (size_t)out_size * 4, stream);
  hipMemsetAsync(counts, 0, 64, stream);

  k_convert_x<<<NT * DD / 4 / 256, 256, 0, stream>>>(x, Xb);
  k_transpose<<<dim3(HH / 32, DD / 32, NE), dim3(32, 8), 0, stream>>>(W1, W1T, DD, HH);
  k_transpose<<<dim3(DD / 32, HH / 32, NE), dim3(32, 8), 0, stream>>>(W2, W2T, HH, DD);
  k_router<<<NT / 4, 256, 0, stream>>>(x, Wr, gate, lists, counts, auxpart);
  k_finalize<<<1, 256, 0, stream>>>(counts, offs, auxpart, out + (size_t)NT * DD);
  k_moe_gemm<DD, HH, true><<<dim3(HH / 256, 32, NE), 512, 0, stream>>>(
      Xb, W1T, Hb, nullptr, lists, counts, offs, gate);
  k_moe_gemm<HH, DD, false><<<dim3(DD / 256, 32, NE), 512, 0, stream>>>(
      Hb, W2T, nullptr, out, lists, counts, offs, gate);
}